// Round 6
// baseline (443.633 us; speedup 1.0000x reference)
//
#include <hip/hip_runtime.h>
#include <stdint.h>

// FAVOR+ attention forward, MI355X. Round 6: fused (Wq@rf^T) feature-GEMM.
// B=4 S=4096 H=8 KD=64 D=512 R=256 CHUNK=128 NC=32

namespace {
constexpr int kB = 4;
constexpr int kS = 4096;
constexpr int kH = 8;
constexpr int kD = 512;   // H*KD
constexpr int kR = 256;
constexpr int kNC = 32;   // S / 128
constexpr float kEPS = 1e-3f;
constexpr float kSCALE = 0.125f;  // 1/sqrt(64)
constexpr int kSP = 80;          // augmented state rows (64 d + 1 Z + 15 pad)
constexpr int kSST = kSP * 256;  // 20480 elements per (bh, c) state
}

typedef __attribute__((ext_vector_type(8))) short bf16x8;
typedef __attribute__((ext_vector_type(4))) float f32x4;

__device__ __forceinline__ f32x4 mfma16(bf16x8 a, bf16x8 b, f32x4 c) {
  return __builtin_amdgcn_mfma_f32_16x16x32_bf16(a, b, c, 0, 0, 0);
}

__device__ __forceinline__ float bflo(uint32_t w) {
  union { uint32_t u; float f; } c; c.u = w << 16; return c.f;
}
__device__ __forceinline__ float bfhi(uint32_t w) {
  union { uint32_t u; float f; } c; c.u = w & 0xffff0000u; return c.f;
}
__device__ __forceinline__ uint16_t f2bf(float x) {  // RNE
  union { float f; uint32_t i; } c; c.f = x;
  uint32_t r = c.i + 0x7fffu + ((c.i >> 16) & 1u);
  return (uint16_t)(r >> 16);
}

// ---------------- prep: cast x, rf, Wq, Wk to bf16 ---------------------------
__global__ __launch_bounds__(256) void cast_inputs(
    const float* __restrict__ x, const float* __restrict__ rfm,
    const float* __restrict__ Wq, const float* __restrict__ Wk,
    uint16_t* __restrict__ x16, uint16_t* __restrict__ rf16,
    uint16_t* __restrict__ Wq16, uint16_t* __restrict__ Wk16)
{
  int i4 = blockIdx.x * 256 + threadIdx.x;
  const int n1 = 2097152;  // x float4 count
  const int n2 = 4096;     // rf
  const int n3 = 65536;    // Wq
  const float* src; uint16_t* dst; int off;
  if (i4 < n1) { src = x; dst = x16; off = i4; }
  else if (i4 < n1 + n2) { src = rfm; dst = rf16; off = i4 - n1; }
  else if (i4 < n1 + n2 + n3) { src = Wq; dst = Wq16; off = i4 - n1 - n2; }
  else { src = Wk; dst = Wk16; off = i4 - n1 - n2 - n3; }
  float4 v = *(const float4*)(src + (size_t)off * 4);
  uint2 o;
  o.x = (uint32_t)f2bf(v.x) | ((uint32_t)f2bf(v.y) << 16);
  o.y = (uint32_t)f2bf(v.z) | ((uint32_t)f2bf(v.w) << 16);
  *(uint2*)(dst + (size_t)off * 4) = o;
}

// ---------------- prep: Wt16[z][n][k] = bf16(W_z[k][n]), z in {Wv, Wo} ------
__global__ __launch_bounds__(256) void transpose_w(
    const float* __restrict__ Wv, const float* __restrict__ Wo,
    uint16_t* __restrict__ WtBase)
{
  __shared__ uint16_t t16[64][72];
  const int z = blockIdx.z;
  const float* W = z ? Wo : Wv;
  uint16_t* Wt = WtBase + (size_t)z * 262144;
  const int tid = threadIdx.x;
  const int k0 = blockIdx.x * 64, n0 = blockIdx.y * 64;
#pragma unroll
  for (int i = 0; i < 4; ++i) {
    int idx = tid + 256 * i;
    int kk = idx >> 4, nn4 = (idx & 15) * 4;
    float4 v = *(const float4*)(W + (size_t)(k0 + kk) * 512 + n0 + nn4);
    t16[kk][nn4 + 0] = f2bf(v.x);
    t16[kk][nn4 + 1] = f2bf(v.y);
    t16[kk][nn4 + 2] = f2bf(v.z);
    t16[kk][nn4 + 3] = f2bf(v.w);
  }
  __syncthreads();
#pragma unroll
  for (int i = 0; i < 4; ++i) {
    int idx = tid + 256 * i;
    int nn = idx >> 4, kk4 = (idx & 15) * 4;
    uint2 o;
    o.x = (uint32_t)t16[kk4 + 0][nn] | ((uint32_t)t16[kk4 + 1][nn] << 16);
    o.y = (uint32_t)t16[kk4 + 2][nn] | ((uint32_t)t16[kk4 + 3][nn] << 16);
    *(uint2*)(Wt + (size_t)(n0 + nn) * 512 + k0 + kk4) = o;
  }
}

// ---------------- prep: Wrf_t[z][h*256+r][k] = Σ_d W16[k][h64+d]·rf16[r][d] --
// grid (4, 8, 2), block 256 = 4 waves; wave w: r-rows [bx*64 + w*16, +16).
__global__ __launch_bounds__(256) void make_wrf(
    const uint16_t* __restrict__ Wq16, const uint16_t* __restrict__ Wk16,
    const uint16_t* __restrict__ rf16, uint16_t* __restrict__ WrfBase)
{
  __shared__ uint16_t tr[4][16][136];  // 17408 B
  const uint16_t* W16 = blockIdx.z ? Wk16 : Wq16;
  uint16_t* out = WrfBase + (size_t)blockIdx.z * 1048576;
  const int h = blockIdx.y;
  const int tid = threadIdx.x;
  const int w = tid >> 6, lane = tid & 63;
  const int lr = lane & 15, lg = lane >> 4;
  const int r0 = blockIdx.x * 64 + w * 16;

  bf16x8 a0 = *(const bf16x8*)(rf16 + (size_t)(r0 + lr) * 64 + 8 * lg);
  bf16x8 a1 = *(const bf16x8*)(rf16 + (size_t)(r0 + lr) * 64 + 32 + 8 * lg);

  for (int kb = 0; kb < 4; ++kb) {  // k-cols [kb*128, +128)
    f32x4 acc[8];
#pragma unroll
    for (int nf = 0; nf < 8; ++nf) acc[nf] = (f32x4){0.f, 0.f, 0.f, 0.f};
#pragma unroll
    for (int nf = 0; nf < 8; ++nf) {
      int kcol = kb * 128 + nf * 16 + lr;
      bf16x8 b0 = *(const bf16x8*)(W16 + (size_t)kcol * 512 + h * 64 + 8 * lg);
      bf16x8 b1 = *(const bf16x8*)(W16 + (size_t)kcol * 512 + h * 64 + 32 + 8 * lg);
      acc[nf] = mfma16(a0, b0, acc[nf]);
      acc[nf] = mfma16(a1, b1, acc[nf]);
    }
#pragma unroll
    for (int nf = 0; nf < 8; ++nf)
#pragma unroll
      for (int reg = 0; reg < 4; ++reg)
        tr[w][4 * lg + reg][nf * 16 + lr] = f2bf(acc[nf][reg]);
    // wave-local coalesced store: 16 rows x 128 cols
#pragma unroll
    for (int it = 0; it < 4; ++it) {
      int idx = it * 64 + lane;
      int row = idx >> 4, c8 = (idx & 15) * 8;
      uint4 val = *(const uint4*)&tr[w][row][c8];
      *(uint4*)(out + (size_t)(h * 256 + r0 + row) * 512 + kb * 128 + c8) = val;
    }
  }
}

// ---------------- bf16 MFMA GEMM: O = A[M,512] @ Bt^T (+bias) ---------------
// Bt is [n][k]. grid (M/128, 512/64), block 256 (4 waves x 32 rows).
template <bool BF16OUT>
__global__ __launch_bounds__(256) void gemm_bf16(
    const uint16_t* __restrict__ A, const uint16_t* __restrict__ Bt,
    const float* __restrict__ bias, void* __restrict__ O)
{
  const int tid = threadIdx.x;
  const int w = tid >> 6, lane = tid & 63;
  const int lr = lane & 15, lg = lane >> 4;
  const int m_base = blockIdx.x * 128 + w * 32;
  const int n_base = blockIdx.y * 64;

  f32x4 acc[2][4];
#pragma unroll
  for (int mf = 0; mf < 2; ++mf)
#pragma unroll
    for (int nf = 0; nf < 4; ++nf) acc[mf][nf] = (f32x4){0.f, 0.f, 0.f, 0.f};

  const uint16_t* a0p = A + (size_t)(m_base + lr) * 512 + 8 * lg;
  const uint16_t* a1p = a0p + (size_t)16 * 512;
  const uint16_t* bp = Bt + (size_t)(n_base + lr) * 512 + 8 * lg;

#pragma unroll
  for (int ks = 0; ks < 16; ++ks) {
    bf16x8 a0 = *(const bf16x8*)(a0p + ks * 32);
    bf16x8 a1 = *(const bf16x8*)(a1p + ks * 32);
#pragma unroll
    for (int nf = 0; nf < 4; ++nf) {
      bf16x8 b = *(const bf16x8*)(bp + (size_t)nf * 16 * 512 + ks * 32);
      acc[0][nf] = mfma16(a0, b, acc[0][nf]);
      acc[1][nf] = mfma16(a1, b, acc[1][nf]);
    }
  }

  float badd[4];
#pragma unroll
  for (int nf = 0; nf < 4; ++nf)
    badd[nf] = bias ? bias[n_base + nf * 16 + lr] : 0.0f;

  if constexpr (BF16OUT) {
    __shared__ uint16_t tr[4][32][72];  // 18432 B
#pragma unroll
    for (int mf = 0; mf < 2; ++mf)
#pragma unroll
      for (int nf = 0; nf < 4; ++nf)
#pragma unroll
        for (int reg = 0; reg < 4; ++reg)
          tr[w][mf * 16 + 4 * lg + reg][nf * 16 + lr] = f2bf(acc[mf][nf][reg] + badd[nf]);
    __syncthreads();
#pragma unroll
    for (int it = 0; it < 4; ++it) {
      int idx = it * 64 + lane;
      int row = idx >> 3, c8 = (idx & 7) * 8;
      uint4 val = *(const uint4*)&tr[w][row][c8];
      *(uint4*)((uint16_t*)O + (size_t)(m_base + row) * 512 + n_base + c8) = val;
    }
  } else {
    __shared__ float trf[4][32][68];  // 34816 B
#pragma unroll
    for (int mf = 0; mf < 2; ++mf)
#pragma unroll
      for (int nf = 0; nf < 4; ++nf)
#pragma unroll
        for (int reg = 0; reg < 4; ++reg)
          trf[w][mf * 16 + 4 * lg + reg][nf * 16 + lr] = acc[mf][nf][reg] + badd[nf];
    __syncthreads();
#pragma unroll
    for (int it = 0; it < 8; ++it) {
      int idx = it * 64 + lane;
      int row = idx >> 4, c4 = (idx & 15) * 4;
      float4 val = *(const float4*)&trf[w][row][c4];
      *(float4*)((float*)O + (size_t)(m_base + row) * 512 + n_base + c4) = val;
    }
  }
}

// ---------------- fused feature GEMM -----------------------------------------
// out[t][h][r] = exp((x16 @ Wrf_h^T)*SCALE - rowmax) + EPS, bf16.
// grid (128, 8, 2); block 256 = 4 waves x 32 rows; B staged in swizzled LDS.
__global__ __launch_bounds__(256) void qkf_gemm(
    const uint16_t* __restrict__ x16, const uint16_t* __restrict__ WrfBase,
    uint16_t* __restrict__ qf, uint16_t* __restrict__ kf)
{
  __shared__ uint16_t Bs[256 * 32];    // 16384 B, XOR-swizzled
  __shared__ uint16_t tr[4][16][264];  // 33792 B
  const uint16_t* Bt = WrfBase + (size_t)blockIdx.z * 1048576 +
                       (size_t)blockIdx.y * 256 * 512;
  uint16_t* dst = blockIdx.z ? kf : qf;
  const int h = blockIdx.y;
  const int tid = threadIdx.x;
  const int w = tid >> 6, lane = tid & 63;
  const int lr = lane & 15, lg = lane >> 4;
  const int m_base = blockIdx.x * 128 + w * 32;

  f32x4 acc[2][16];
#pragma unroll
  for (int mf = 0; mf < 2; ++mf)
#pragma unroll
    for (int nf = 0; nf < 16; ++nf) acc[mf][nf] = (f32x4){0.f, 0.f, 0.f, 0.f};

  const uint16_t* a0p = x16 + (size_t)(m_base + lr) * 512 + 8 * lg;

  for (int ks = 0; ks < 16; ++ks) {
    __syncthreads();
#pragma unroll
    for (int i = 0; i < 4; ++i) {  // stage 256 rows x 32 k-elems (16 KB)
      int idx = tid + 256 * i;
      int row = idx >> 2, j = idx & 3;
      uint4 v = *(const uint4*)(Bt + (size_t)row * 512 + ks * 32 + j * 8);
      int byteoff = row * 64 + ((j * 16) ^ (((row >> 1) & 3) << 4));
      *(uint4*)((char*)Bs + byteoff) = v;
    }
    __syncthreads();
    bf16x8 a0 = *(const bf16x8*)(a0p + ks * 32);
    bf16x8 a1 = *(const bf16x8*)(a0p + 16 * 512 + ks * 32);
#pragma unroll
    for (int nf = 0; nf < 16; ++nf) {
      int row = nf * 16 + lr;
      int byteoff = row * 64 + ((lg * 16) ^ (((row >> 1) & 3) << 4));
      bf16x8 b = *(const bf16x8*)((char*)Bs + byteoff);
      acc[0][nf] = mfma16(a0, b, acc[0][nf]);
      acc[1][nf] = mfma16(a1, b, acc[1][nf]);
    }
  }

  // epilogue: scale, rowmax over all 256 r, exp + eps, coalesced store
#pragma unroll
  for (int mf = 0; mf < 2; ++mf) {
    float mx[4] = {-1e30f, -1e30f, -1e30f, -1e30f};
#pragma unroll
    for (int nf = 0; nf < 16; ++nf)
#pragma unroll
      for (int reg = 0; reg < 4; ++reg) {
        acc[mf][nf][reg] *= kSCALE;
        mx[reg] = fmaxf(mx[reg], acc[mf][nf][reg]);
      }
#pragma unroll
    for (int reg = 0; reg < 4; ++reg) {
      mx[reg] = fmaxf(mx[reg], __shfl_xor(mx[reg], 1));
      mx[reg] = fmaxf(mx[reg], __shfl_xor(mx[reg], 2));
      mx[reg] = fmaxf(mx[reg], __shfl_xor(mx[reg], 4));
      mx[reg] = fmaxf(mx[reg], __shfl_xor(mx[reg], 8));
    }
#pragma unroll
    for (int nf = 0; nf < 16; ++nf)
#pragma unroll
      for (int reg = 0; reg < 4; ++reg)
        tr[w][4 * lg + reg][nf * 16 + lr] =
            f2bf(__expf(acc[mf][nf][reg] - mx[reg]) + kEPS);
    // wave-local: LDS ops are in-order per wave, no block sync needed
#pragma unroll
    for (int it = 0; it < 8; ++it) {
      int idx = it * 64 + lane;
      int row = idx >> 5, c8 = (idx & 31) * 8;
      uint4 val = *(const uint4*)&tr[w][row][c8];
      size_t t = (size_t)m_base + mf * 16 + row;
      *(uint4*)(dst + (t * 8 + h) * 256 + c8) = val;
    }
  }
}

// ---------------- chunk_sum via MFMA -----------------------------------------
// Skv_t[bh][c][80][256]: rows 0..63 = V^T KF; row 64 = Z; 65..79 = 0.
__global__ __launch_bounds__(256) void chunk_mfma(
    const uint16_t* __restrict__ kfeat, const uint16_t* __restrict__ vbuf,
    uint16_t* __restrict__ Skv)
{
  __shared__ uint16_t Vaug[80][136];
  __shared__ uint16_t uni2[21120];  // 42240 B
  uint16_t (*kfT)[72] = (uint16_t (*)[72])uni2;
  uint16_t (*outT)[264] = (uint16_t (*)[264])uni2;

  const int c = blockIdx.x, bh = blockIdx.y;
  const int b = bh >> 3, h = bh & 7;
  const int tid = threadIdx.x;
  const int w = tid >> 6, lane = tid & 63;
  const int lr = lane & 15, lg = lane >> 4;
  const size_t srow = (size_t)b * kS + (size_t)c * 128;

#pragma unroll
  for (int i = 0; i < 4; ++i) {
    int idx = tid + 256 * i;
    int u = idx & 127, d = (idx >> 7) * 8;
    uint4 w8 = *(const uint4*)(vbuf + (srow + u) * kD + h * 64 + d);
    Vaug[d + 0][u] = (uint16_t)(w8.x & 0xffff);
    Vaug[d + 1][u] = (uint16_t)(w8.x >> 16);
    Vaug[d + 2][u] = (uint16_t)(w8.y & 0xffff);
    Vaug[d + 3][u] = (uint16_t)(w8.y >> 16);
    Vaug[d + 4][u] = (uint16_t)(w8.z & 0xffff);
    Vaug[d + 5][u] = (uint16_t)(w8.z >> 16);
    Vaug[d + 6][u] = (uint16_t)(w8.w & 0xffff);
    Vaug[d + 7][u] = (uint16_t)(w8.w >> 16);
  }
  if (tid < 128) Vaug[64][tid] = 0x3F80;  // bf16(1.0)
  if (tid < 136) {
#pragma unroll
    for (int rr = 65; rr < 80; ++rr) Vaug[rr][tid] = 0;
  }

  f32x4 acc[5][4];
#pragma unroll
  for (int mf = 0; mf < 5; ++mf)
#pragma unroll
    for (int nf = 0; nf < 4; ++nf) acc[mf][nf] = (f32x4){0.f, 0.f, 0.f, 0.f};

  const uint16_t* kp0 = kfeat + (srow * kH + h) * kR;
#pragma unroll
  for (int th = 0; th < 2; ++th) {
    if (th) __syncthreads();
    const uint16_t* kp = kp0 + (size_t)th * 64 * (kH * kR);
#pragma unroll
    for (int i = 0; i < 16; ++i) {
      int idx = tid + 256 * i;
      int t = idx >> 6, c4 = idx & 63;
      uint2 wv = *(const uint2*)(kp + (size_t)t * (kH * kR) + c4 * 4);
      int r = c4 * 4;
      kfT[r + 0][t] = (uint16_t)(wv.x & 0xffff);
      kfT[r + 1][t] = (uint16_t)(wv.x >> 16);
      kfT[r + 2][t] = (uint16_t)(wv.y & 0xffff);
      kfT[r + 3][t] = (uint16_t)(wv.y >> 16);
    }
    __syncthreads();
#pragma unroll
    for (int ks = 0; ks < 2; ++ks) {
      bf16x8 af[5];
#pragma unroll
      for (int mf = 0; mf < 5; ++mf)
        af[mf] = *(const bf16x8*)&Vaug[mf * 16 + lr][th * 64 + ks * 32 + 8 * lg];
#pragma unroll
      for (int nf = 0; nf < 4; ++nf) {
        bf16x8 kb = *(const bf16x8*)&kfT[w * 64 + nf * 16 + lr][ks * 32 + 8 * lg];
#pragma unroll
        for (int mf = 0; mf < 5; ++mf)
          acc[mf][nf] = mfma16(af[mf], kb, acc[mf][nf]);
      }
    }
  }

  __syncthreads();  // kfT dead -> reuse as outT
#pragma unroll
  for (int mf = 0; mf < 5; ++mf)
#pragma unroll
    for (int nf = 0; nf < 4; ++nf)
#pragma unroll
      for (int reg = 0; reg < 4; ++reg)
        outT[mf * 16 + 4 * lg + reg][w * 64 + nf * 16 + lr] = f2bf(acc[mf][nf][reg]);
  __syncthreads();

  uint16_t* So = Skv + ((size_t)bh * kNC + c) * kSST;
#pragma unroll
  for (int it = 0; it < 10; ++it) {
    int idx = tid + 256 * it;
    int row = idx >> 5, c8 = (idx & 31) * 8;
    uint4 val = *(const uint4*)&outT[row][c8];
    *(uint4*)(So + (size_t)row * 256 + c8) = val;
  }
}

// ---------------- exclusive prefix over chunks (in place) --------------------
__global__ __launch_bounds__(256) void prefix_kernel(uint16_t* __restrict__ Skv)
{
  int e = blockIdx.x * 256 + threadIdx.x;  // 32 bh * 20480
  int bh = e / kSST;
  int rd = e - bh * kSST;
  size_t base = (size_t)bh * kNC * kSST + rd;
  float run = 0.f;
  for (int c = 0; c < kNC; ++c) {
    size_t idx = base + (size_t)c * kSST;
    union { uint32_t i; float f; } cv; cv.i = ((uint32_t)Skv[idx]) << 16;
    Skv[idx] = f2bf(run);
    run += cv.f;
  }
}

// ---------------- favor_out via MFMA -----------------------------------------
__global__ __launch_bounds__(256) void favor_mfma(
    const uint16_t* __restrict__ qfeat, const uint16_t* __restrict__ kfeat,
    const uint16_t* __restrict__ vbuf, const uint16_t* __restrict__ Skv,
    uint16_t* __restrict__ attn16)
{
  __shared__ uint16_t Vaug[80][136];     // 21760 B
  __shared__ uint16_t A_l[4][32][40];    // 10240 B

  const int c = blockIdx.x, bh = blockIdx.y;
  const int b = bh >> 3, h = bh & 7;
  const int tid = threadIdx.x;
  const int w = tid >> 6, lane = tid & 63;
  const int lr = lane & 15, lg = lane >> 4;
  const size_t srow = (size_t)b * kS + (size_t)c * 128;

#pragma unroll
  for (int i = 0; i < 4; ++i) {
    int idx = tid + 256 * i;
    int u = idx & 127, d = (idx >> 7) * 8;
    uint4 w8 = *(const uint4*)(vbuf + (srow + u) * kD + h * 64 + d);
    Vaug[d + 0][u] = (uint16_t)(w8.x & 0xffff);
    Vaug[d + 1][u] = (uint16_t)(w8.x >> 16);
    Vaug[d + 2][u] = (uint16_t)(w8.y & 0xffff);
    Vaug[d + 3][u] = (uint16_t)(w8.y >> 16);
    Vaug[d + 4][u] = (uint16_t)(w8.z & 0xffff);
    Vaug[d + 5][u] = (uint16_t)(w8.z >> 16);
    Vaug[d + 6][u] = (uint16_t)(w8.w & 0xffff);
    Vaug[d + 7][u] = (uint16_t)(w8.w >> 16);
  }
  if (tid < 128) Vaug[64][tid] = 0x3F80;
  if (tid < 136) {
#pragma unroll
    for (int rr = 65; rr < 80; ++rr) Vaug[rr][tid] = 0;
  }

  bf16x8 qa[2][8];
  const uint16_t* qp = qfeat + ((srow + w * 32 + lr) * kH + h) * kR + 8 * lg;
#pragma unroll
  for (int mf = 0; mf < 2; ++mf)
#pragma unroll
    for (int ks = 0; ks < 8; ++ks)
      qa[mf][ks] = *(const bf16x8*)(qp + (size_t)mf * 16 * (kH * kR) + ks * 32);

  f32x4 o[2][5];
#pragma unroll
  for (int mf = 0; mf < 2; ++mf)
#pragma unroll
    for (int nf = 0; nf < 5; ++nf) o[mf][nf] = (f32x4){0.f, 0.f, 0.f, 0.f};

  const uint16_t* Sg = Skv + ((size_t)bh * kNC + c) * kSST + 8 * lg;
#pragma unroll
  for (int ks = 0; ks < 8; ++ks) {
#pragma unroll
    for (int nf = 0; nf < 5; ++nf) {
      bf16x8 sb = *(const bf16x8*)(Sg + (size_t)(nf * 16 + lr) * 256 + ks * 32);
      o[0][nf] = mfma16(qa[0][ks], sb, o[0][nf]);
      o[1][nf] = mfma16(qa[1][ks], sb, o[1][nf]);
    }
  }

  __syncthreads();

  const uint16_t* kp = kfeat + (srow + lr) * (kH * kR) + h * kR + 8 * lg;
  for (int ut = 0; ut <= w; ++ut) {
    f32x4 aacc[2][2];
#pragma unroll
    for (int mf = 0; mf < 2; ++mf)
#pragma unroll
      for (int nf = 0; nf < 2; ++nf) aacc[mf][nf] = (f32x4){0.f, 0.f, 0.f, 0.f};
#pragma unroll
    for (int ks = 0; ks < 8; ++ks) {
      bf16x8 kb0 = *(const bf16x8*)(kp + (size_t)(ut * 32) * (kH * kR) + ks * 32);
      bf16x8 kb1 = *(const bf16x8*)(kp + (size_t)(ut * 32 + 16) * (kH * kR) + ks * 32);
      aacc[0][0] = mfma16(qa[0][ks], kb0, aacc[0][0]);
      aacc[0][1] = mfma16(qa[0][ks], kb1, aacc[0][1]);
      aacc[1][0] = mfma16(qa[1][ks], kb0, aacc[1][0]);
      aacc[1][1] = mfma16(qa[1][ks], kb1, aacc[1][1]);
    }
#pragma unroll
    for (int mf = 0; mf < 2; ++mf)
#pragma unroll
      for (int nf = 0; nf < 2; ++nf)
#pragma unroll
        for (int reg = 0; reg < 4; ++reg) {
          int trow = mf * 16 + 4 * lg + reg;
          int ucol = nf * 16 + lr;
          float v = aacc[mf][nf][reg];
          if (ut == w && ucol > trow) v = 0.0f;
          A_l[w][trow][ucol] = f2bf(v);
        }
    bf16x8 af0 = *(const bf16x8*)&A_l[w][lr][8 * lg];
    bf16x8 af1 = *(const bf16x8*)&A_l[w][16 + lr][8 * lg];
#pragma unroll
    for (int nf = 0; nf < 5; ++nf) {
      bf16x8 vb = *(const bf16x8*)&Vaug[nf * 16 + lr][ut * 32 + 8 * lg];
      o[0][nf] = mfma16(af0, vb, o[0][nf]);
      o[1][nf] = mfma16(af1, vb, o[1][nf]);
    }
  }

#pragma unroll
  for (int mf = 0; mf < 2; ++mf) {
    float inv[4];
#pragma unroll
    for (int reg = 0; reg < 4; ++reg) {
      float den = __shfl(o[mf][4][reg], lane & 48);
      inv[reg] = 1.0f / (den + kEPS);
    }
    const size_t trow = srow + w * 32 + mf * 16 + 4 * lg;
#pragma unroll
    for (int reg = 0; reg < 4; ++reg) {
      uint16_t* op = attn16 + (trow + reg) * kD + h * 64 + lr;
#pragma unroll
      for (int nf = 0; nf < 4; ++nf)
        op[nf * 16] = f2bf(o[mf][nf][reg] * inv[reg]);
    }
  }
}

// ---------------- launch -----------------------------------------------------
extern "C" void kernel_launch(void* const* d_in, const int* in_sizes, int n_in,
                              void* d_out, int out_size, void* d_ws, size_t ws_size,
                              hipStream_t stream)
{
  (void)in_sizes; (void)n_in; (void)out_size; (void)ws_size;
  const float* x  = (const float*)d_in[0];
  const float* Wq = (const float*)d_in[1];
  const float* Wk = (const float*)d_in[2];
  const float* Wv = (const float*)d_in[3];
  const float* Wo = (const float*)d_in[4];
  const float* bo = (const float*)d_in[5];
  const float* rf = (const float*)d_in[6];
  float* out = (float*)d_out;

  const size_t MiB = 1048576;
  char* ws = (char*)d_ws;
  uint16_t* x16    = (uint16_t*)ws;                    // 16 MiB
  uint16_t* attn16 = (uint16_t*)(ws + 16 * MiB);       // 16 MiB
  uint16_t* v16    = (uint16_t*)(ws + 32 * MiB);       // 16 MiB
  uint16_t* qf     = (uint16_t*)(ws + 48 * MiB);       // 64 MiB
  uint16_t* kf     = (uint16_t*)(ws + 112 * MiB);      // 64 MiB
  uint16_t* Skv    = (uint16_t*)(ws + 176 * MiB);      // 40 MiB
  uint16_t* Wt     = (uint16_t*)(ws + 216 * MiB);      // 1 MiB (Wv^T, Wo^T)
  uint16_t* Wrf    = (uint16_t*)(ws + 217 * MiB);      // 4 MiB (q, k)
  uint16_t* Wq16   = (uint16_t*)(ws + 221 * MiB);      // 0.5 MiB
  uint16_t* Wk16   = Wq16 + 262144;                    // 0.5 MiB
  uint16_t* rf16   = (uint16_t*)(ws + 222 * MiB);      // 32 KiB

  cast_inputs<<<dim3(8720, 1, 1), 256, 0, stream>>>(x, rf, Wq, Wk,
                                                    x16, rf16, Wq16, Wk16);
  transpose_w<<<dim3(8, 8, 2), 256, 0, stream>>>(Wv, Wo, Wt);
  make_wrf<<<dim3(4, 8, 2), 256, 0, stream>>>(Wq16, Wk16, rf16, Wrf);

  gemm_bf16<true><<<dim3(128, 8, 1), 256, 0, stream>>>(x16, Wt, nullptr, v16);
  qkf_gemm<<<dim3(128, 8, 2), 256, 0, stream>>>(x16, Wrf, qf, kf);

  chunk_mfma<<<dim3(kNC, kB * kH, 1), 256, 0, stream>>>(kf, v16, Skv);
  prefix_kernel<<<dim3(2560, 1, 1), 256, 0, stream>>>(Skv);
  favor_mfma<<<dim3(kNC, kB * kH, 1), 256, 0, stream>>>(qf, kf, v16, Skv, attn16);

  gemm_bf16<false><<<dim3(128, 8, 1), 256, 0, stream>>>(attn16, Wt + 262144, bo, out);
}

// Round 7
// 326.849 us; speedup vs baseline: 1.3573x; 1.3573x over previous
//
#include <hip/hip_runtime.h>
#include <stdint.h>

// FAVOR+ attention forward, MI355X. Round 7: feat fused into q/k projection GEMM.
// B=4 S=4096 H=8 KD=64 D=512 R=256 CHUNK=128 NC=32

namespace {
constexpr int kB = 4;
constexpr int kS = 4096;
constexpr int kH = 8;
constexpr int kD = 512;   // H*KD
constexpr int kR = 256;
constexpr int kNC = 32;   // S / 128
constexpr float kEPS = 1e-3f;
constexpr int kSP = 80;          // augmented state rows (64 d + 1 Z + 15 pad)
constexpr int kSST = kSP * 256;  // 20480 elements per (bh, c) state
}

typedef __attribute__((ext_vector_type(8))) short bf16x8;
typedef __attribute__((ext_vector_type(4))) float f32x4;

__device__ __forceinline__ f32x4 mfma16(bf16x8 a, bf16x8 b, f32x4 c) {
  return __builtin_amdgcn_mfma_f32_16x16x32_bf16(a, b, c, 0, 0, 0);
}

__device__ __forceinline__ uint16_t f2bf(float x) {  // RNE
  union { float f; uint32_t i; } c; c.f = x;
  uint32_t r = c.i + 0x7fffu + ((c.i >> 16) & 1u);
  return (uint16_t)(r >> 16);
}

// ---------------- prep: cast x and rf to bf16 --------------------------------
__global__ __launch_bounds__(256) void cast_inputs(
    const float* __restrict__ x, const float* __restrict__ rfm,
    uint16_t* __restrict__ x16, uint16_t* __restrict__ rf16)
{
  int i4 = blockIdx.x * 256 + threadIdx.x;
  const int n1 = 2097152;  // x float4 count
  const int n2 = 4096;     // rf
  const float* src; uint16_t* dst; int off;
  if (i4 < n1) { src = x; dst = x16; off = i4; }
  else if (i4 < n1 + n2) { src = rfm; dst = rf16; off = i4 - n1; }
  else return;
  float4 v = *(const float4*)(src + (size_t)off * 4);
  uint2 o;
  o.x = (uint32_t)f2bf(v.x) | ((uint32_t)f2bf(v.y) << 16);
  o.y = (uint32_t)f2bf(v.z) | ((uint32_t)f2bf(v.w) << 16);
  *(uint2*)(dst + (size_t)off * 4) = o;
}

// ---------------- prep: Wt16[z][n][k] = bf16(W_z[k][n]), z in {Wq,Wk,Wv,Wo} -
__global__ __launch_bounds__(256) void transpose_w(
    const float* __restrict__ Wq, const float* __restrict__ Wk,
    const float* __restrict__ Wv, const float* __restrict__ Wo,
    uint16_t* __restrict__ WtBase)
{
  __shared__ uint16_t t16[64][72];
  const int z = blockIdx.z;
  const float* W = (z == 0) ? Wq : (z == 1) ? Wk : (z == 2) ? Wv : Wo;
  uint16_t* Wt = WtBase + (size_t)z * 262144;
  const int tid = threadIdx.x;
  const int k0 = blockIdx.x * 64, n0 = blockIdx.y * 64;
#pragma unroll
  for (int i = 0; i < 4; ++i) {
    int idx = tid + 256 * i;
    int kk = idx >> 4, nn4 = (idx & 15) * 4;
    float4 v = *(const float4*)(W + (size_t)(k0 + kk) * 512 + n0 + nn4);
    t16[kk][nn4 + 0] = f2bf(v.x);
    t16[kk][nn4 + 1] = f2bf(v.y);
    t16[kk][nn4 + 2] = f2bf(v.z);
    t16[kk][nn4 + 3] = f2bf(v.w);
  }
  __syncthreads();
#pragma unroll
  for (int i = 0; i < 4; ++i) {
    int idx = tid + 256 * i;
    int nn = idx >> 4, kk4 = (idx & 15) * 4;
    uint2 o;
    o.x = (uint32_t)t16[kk4 + 0][nn] | ((uint32_t)t16[kk4 + 1][nn] << 16);
    o.y = (uint32_t)t16[kk4 + 2][nn] | ((uint32_t)t16[kk4 + 3][nn] << 16);
    *(uint2*)(Wt + (size_t)(n0 + nn) * 512 + k0 + kk4) = o;
  }
}

// ---------------- bf16 MFMA GEMM: O = A[M,512] @ Bt^T (+bias) ---------------
// Bt is [n][k]. grid (M/128, 512/64), block 256 (4 waves x 32 rows).
template <bool BF16OUT>
__global__ __launch_bounds__(256) void gemm_bf16(
    const uint16_t* __restrict__ A, const uint16_t* __restrict__ Bt,
    const float* __restrict__ bias, void* __restrict__ O)
{
  const int tid = threadIdx.x;
  const int w = tid >> 6, lane = tid & 63;
  const int lr = lane & 15, lg = lane >> 4;
  const int m_base = blockIdx.x * 128 + w * 32;
  const int n_base = blockIdx.y * 64;

  f32x4 acc[2][4];
#pragma unroll
  for (int mf = 0; mf < 2; ++mf)
#pragma unroll
    for (int nf = 0; nf < 4; ++nf) acc[mf][nf] = (f32x4){0.f, 0.f, 0.f, 0.f};

  const uint16_t* a0p = A + (size_t)(m_base + lr) * 512 + 8 * lg;
  const uint16_t* a1p = a0p + (size_t)16 * 512;
  const uint16_t* bp = Bt + (size_t)(n_base + lr) * 512 + 8 * lg;

#pragma unroll
  for (int ks = 0; ks < 16; ++ks) {
    bf16x8 a0 = *(const bf16x8*)(a0p + ks * 32);
    bf16x8 a1 = *(const bf16x8*)(a1p + ks * 32);
#pragma unroll
    for (int nf = 0; nf < 4; ++nf) {
      bf16x8 b = *(const bf16x8*)(bp + (size_t)nf * 16 * 512 + ks * 32);
      acc[0][nf] = mfma16(a0, b, acc[0][nf]);
      acc[1][nf] = mfma16(a1, b, acc[1][nf]);
    }
  }

  float badd[4];
#pragma unroll
  for (int nf = 0; nf < 4; ++nf)
    badd[nf] = bias ? bias[n_base + nf * 16 + lr] : 0.0f;

  if constexpr (BF16OUT) {
    __shared__ uint16_t tr[4][32][72];  // 18432 B
#pragma unroll
    for (int mf = 0; mf < 2; ++mf)
#pragma unroll
      for (int nf = 0; nf < 4; ++nf)
#pragma unroll
        for (int reg = 0; reg < 4; ++reg)
          tr[w][mf * 16 + 4 * lg + reg][nf * 16 + lr] = f2bf(acc[mf][nf][reg] + badd[nf]);
    __syncthreads();
#pragma unroll
    for (int it = 0; it < 4; ++it) {
      int idx = it * 64 + lane;
      int row = idx >> 3, c8 = (idx & 7) * 8;
      uint4 val = *(const uint4*)&tr[w][row][c8];
      *(uint4*)((uint16_t*)O + (size_t)(m_base + row) * 512 + n_base + c8) = val;
    }
  } else {
    __shared__ float trf[4][32][68];  // 34816 B
#pragma unroll
    for (int mf = 0; mf < 2; ++mf)
#pragma unroll
      for (int nf = 0; nf < 4; ++nf)
#pragma unroll
        for (int reg = 0; reg < 4; ++reg)
          trf[w][mf * 16 + 4 * lg + reg][nf * 16 + lr] = acc[mf][nf][reg] + badd[nf];
    __syncthreads();
#pragma unroll
    for (int it = 0; it < 8; ++it) {
      int idx = it * 64 + lane;
      int row = idx >> 4, c4 = (idx & 15) * 4;
      float4 val = *(const float4*)&trf[w][row][c4];
      *(float4*)((float*)O + (size_t)(m_base + row) * 512 + n_base + c4) = val;
    }
  }
}

// ---------------- fused projection + feature kernel --------------------------
// q = x @ Wz (head h cols held in regs) -> p = (q*0.125) @ rf^T -> exp(p-max)+eps
// grid (128, 8, 2); block 256 = 4 waves x 32 rows. LDS 54272 B.
__global__ __launch_bounds__(256) void gemm_feat(
    const uint16_t* __restrict__ x16, const uint16_t* __restrict__ WtBase,
    const uint16_t* __restrict__ rf16,
    uint16_t* __restrict__ qf, uint16_t* __restrict__ kf)
{
  __shared__ uint16_t rf_l[256][72];    // 36864 B
  __shared__ uint16_t trbuf[4][2176];   // 17408 B, per-wave scratch (16x136)

  const uint16_t* Bt = WtBase + (size_t)blockIdx.z * 262144;
  uint16_t* dst = blockIdx.z ? kf : qf;
  const int h = blockIdx.y;
  const int tid = threadIdx.x;
  const int w = tid >> 6, lane = tid & 63;
  const int lr = lane & 15, lg = lane >> 4;
  const int m_base = blockIdx.x * 128 + w * 32;

  // stage rf_l[r][d] (256 x 64)
#pragma unroll
  for (int i = 0; i < 8; ++i) {
    int idx = tid + 256 * i;
    int row = idx >> 3, c8 = (idx & 7) * 8;
    uint4 v = *(const uint4*)(rf16 + (size_t)row * 64 + c8);
    *(uint4*)&rf_l[row][c8] = v;
  }
  __syncthreads();

  // ---- phase 1: projection GEMM, n-slice = head h (64 cols) ----
  f32x4 acc[2][4];
#pragma unroll
  for (int mf = 0; mf < 2; ++mf)
#pragma unroll
    for (int nf = 0; nf < 4; ++nf) acc[mf][nf] = (f32x4){0.f, 0.f, 0.f, 0.f};

  const uint16_t* a0p = x16 + (size_t)(m_base + lr) * 512 + 8 * lg;
  const uint16_t* a1p = a0p + (size_t)16 * 512;
  const uint16_t* bp = Bt + (size_t)(h * 64 + lr) * 512 + 8 * lg;

#pragma unroll
  for (int ks = 0; ks < 16; ++ks) {
    bf16x8 a0 = *(const bf16x8*)(a0p + ks * 32);
    bf16x8 a1 = *(const bf16x8*)(a1p + ks * 32);
#pragma unroll
    for (int nf = 0; nf < 4; ++nf) {
      bf16x8 b = *(const bf16x8*)(bp + (size_t)nf * 16 * 512 + ks * 32);
      acc[0][nf] = mfma16(a0, b, acc[0][nf]);
      acc[1][nf] = mfma16(a1, b, acc[1][nf]);
    }
  }

  // ---- phase 1.5: per-mf wave-local transpose D-frags -> A-frags ----
  // x0.125 folded here: power-of-2 scale, bit-exact vs scaling after.
  uint16_t (*trw)[72] = (uint16_t (*)[72])&trbuf[w][0];
  bf16x8 qa[2][2];
#pragma unroll
  for (int mf = 0; mf < 2; ++mf) {
#pragma unroll
    for (int nf = 0; nf < 4; ++nf)
#pragma unroll
      for (int reg = 0; reg < 4; ++reg)
        trw[4 * lg + reg][nf * 16 + lr] = f2bf(acc[mf][nf][reg] * 0.125f);
    qa[mf][0] = *(const bf16x8*)&trw[lr][8 * lg];
    qa[mf][1] = *(const bf16x8*)&trw[lr][32 + 8 * lg];
  }

  // ---- phase 2: feature GEMM p = q' @ rf^T (K = 64) ----
  f32x4 acc2[2][16];
#pragma unroll
  for (int mf = 0; mf < 2; ++mf)
#pragma unroll
    for (int nf = 0; nf < 16; ++nf) acc2[mf][nf] = (f32x4){0.f, 0.f, 0.f, 0.f};
#pragma unroll
  for (int ks = 0; ks < 2; ++ks) {
#pragma unroll
    for (int nf = 0; nf < 16; ++nf) {
      bf16x8 b = *(const bf16x8*)&rf_l[nf * 16 + lr][ks * 32 + 8 * lg];
      acc2[0][nf] = mfma16(qa[0][ks], b, acc2[0][nf]);
      acc2[1][nf] = mfma16(qa[1][ks], b, acc2[1][nf]);
    }
  }

  // ---- epilogue: rowmax over 256 r, exp + eps, coalesced store ----
  uint16_t (*trh)[136] = (uint16_t (*)[136])&trbuf[w][0];
#pragma unroll
  for (int mf = 0; mf < 2; ++mf) {
    float mx[4] = {-1e30f, -1e30f, -1e30f, -1e30f};
#pragma unroll
    for (int nf = 0; nf < 16; ++nf)
#pragma unroll
      for (int reg = 0; reg < 4; ++reg)
        mx[reg] = fmaxf(mx[reg], acc2[mf][nf][reg]);
#pragma unroll
    for (int reg = 0; reg < 4; ++reg) {
      mx[reg] = fmaxf(mx[reg], __shfl_xor(mx[reg], 1));
      mx[reg] = fmaxf(mx[reg], __shfl_xor(mx[reg], 2));
      mx[reg] = fmaxf(mx[reg], __shfl_xor(mx[reg], 4));
      mx[reg] = fmaxf(mx[reg], __shfl_xor(mx[reg], 8));
    }
#pragma unroll
    for (int half = 0; half < 2; ++half) {
#pragma unroll
      for (int nf8 = 0; nf8 < 8; ++nf8) {
        int nf = half * 8 + nf8;
#pragma unroll
        for (int reg = 0; reg < 4; ++reg)
          trh[4 * lg + reg][nf8 * 16 + lr] =
              f2bf(__expf(acc2[mf][nf][reg] - mx[reg]) + kEPS);
      }
#pragma unroll
      for (int it = 0; it < 4; ++it) {
        int idx = it * 64 + lane;
        int row = idx >> 4, c8 = (idx & 15) * 8;
        uint4 val = *(const uint4*)&trh[row][c8];
        size_t t = (size_t)m_base + mf * 16 + row;
        *(uint4*)(dst + (t * 8 + h) * 256 + half * 128 + c8) = val;
      }
    }
  }
}

// ---------------- chunk_sum via MFMA -----------------------------------------
// Skv_t[bh][c][80][256]: rows 0..63 = V^T KF; row 64 = Z; 65..79 = 0.
__global__ __launch_bounds__(256) void chunk_mfma(
    const uint16_t* __restrict__ kfeat, const uint16_t* __restrict__ vbuf,
    uint16_t* __restrict__ Skv)
{
  __shared__ uint16_t Vaug[80][136];
  __shared__ uint16_t uni2[21120];  // 42240 B
  uint16_t (*kfT)[72] = (uint16_t (*)[72])uni2;
  uint16_t (*outT)[264] = (uint16_t (*)[264])uni2;

  const int c = blockIdx.x, bh = blockIdx.y;
  const int b = bh >> 3, h = bh & 7;
  const int tid = threadIdx.x;
  const int w = tid >> 6, lane = tid & 63;
  const int lr = lane & 15, lg = lane >> 4;
  const size_t srow = (size_t)b * kS + (size_t)c * 128;

#pragma unroll
  for (int i = 0; i < 4; ++i) {
    int idx = tid + 256 * i;
    int u = idx & 127, d = (idx >> 7) * 8;
    uint4 w8 = *(const uint4*)(vbuf + (srow + u) * kD + h * 64 + d);
    Vaug[d + 0][u] = (uint16_t)(w8.x & 0xffff);
    Vaug[d + 1][u] = (uint16_t)(w8.x >> 16);
    Vaug[d + 2][u] = (uint16_t)(w8.y & 0xffff);
    Vaug[d + 3][u] = (uint16_t)(w8.y >> 16);
    Vaug[d + 4][u] = (uint16_t)(w8.z & 0xffff);
    Vaug[d + 5][u] = (uint16_t)(w8.z >> 16);
    Vaug[d + 6][u] = (uint16_t)(w8.w & 0xffff);
    Vaug[d + 7][u] = (uint16_t)(w8.w >> 16);
  }
  if (tid < 128) Vaug[64][tid] = 0x3F80;  // bf16(1.0)
  if (tid < 136) {
#pragma unroll
    for (int rr = 65; rr < 80; ++rr) Vaug[rr][tid] = 0;
  }

  f32x4 acc[5][4];
#pragma unroll
  for (int mf = 0; mf < 5; ++mf)
#pragma unroll
    for (int nf = 0; nf < 4; ++nf) acc[mf][nf] = (f32x4){0.f, 0.f, 0.f, 0.f};

  const uint16_t* kp0 = kfeat + (srow * kH + h) * kR;
#pragma unroll
  for (int th = 0; th < 2; ++th) {
    if (th) __syncthreads();
    const uint16_t* kp = kp0 + (size_t)th * 64 * (kH * kR);
#pragma unroll
    for (int i = 0; i < 16; ++i) {
      int idx = tid + 256 * i;
      int t = idx >> 6, c4 = idx & 63;
      uint2 wv = *(const uint2*)(kp + (size_t)t * (kH * kR) + c4 * 4);
      int r = c4 * 4;
      kfT[r + 0][t] = (uint16_t)(wv.x & 0xffff);
      kfT[r + 1][t] = (uint16_t)(wv.x >> 16);
      kfT[r + 2][t] = (uint16_t)(wv.y & 0xffff);
      kfT[r + 3][t] = (uint16_t)(wv.y >> 16);
    }
    __syncthreads();
#pragma unroll
    for (int ks = 0; ks < 2; ++ks) {
      bf16x8 af[5];
#pragma unroll
      for (int mf = 0; mf < 5; ++mf)
        af[mf] = *(const bf16x8*)&Vaug[mf * 16 + lr][th * 64 + ks * 32 + 8 * lg];
#pragma unroll
      for (int nf = 0; nf < 4; ++nf) {
        bf16x8 kb = *(const bf16x8*)&kfT[w * 64 + nf * 16 + lr][ks * 32 + 8 * lg];
#pragma unroll
        for (int mf = 0; mf < 5; ++mf)
          acc[mf][nf] = mfma16(af[mf], kb, acc[mf][nf]);
      }
    }
  }

  __syncthreads();  // kfT dead -> reuse as outT
#pragma unroll
  for (int mf = 0; mf < 5; ++mf)
#pragma unroll
    for (int nf = 0; nf < 4; ++nf)
#pragma unroll
      for (int reg = 0; reg < 4; ++reg)
        outT[mf * 16 + 4 * lg + reg][w * 64 + nf * 16 + lr] = f2bf(acc[mf][nf][reg]);
  __syncthreads();

  uint16_t* So = Skv + ((size_t)bh * kNC + c) * kSST;
#pragma unroll
  for (int it = 0; it < 10; ++it) {
    int idx = tid + 256 * it;
    int row = idx >> 5, c8 = (idx & 31) * 8;
    uint4 val = *(const uint4*)&outT[row][c8];
    *(uint4*)(So + (size_t)row * 256 + c8) = val;
  }
}

// ---------------- exclusive prefix over chunks (in place) --------------------
__global__ __launch_bounds__(256) void prefix_kernel(uint16_t* __restrict__ Skv)
{
  int e = blockIdx.x * 256 + threadIdx.x;  // 32 bh * 20480
  int bh = e / kSST;
  int rd = e - bh * kSST;
  size_t base = (size_t)bh * kNC * kSST + rd;
  float run = 0.f;
  for (int c = 0; c < kNC; ++c) {
    size_t idx = base + (size_t)c * kSST;
    union { uint32_t i; float f; } cv; cv.i = ((uint32_t)Skv[idx]) << 16;
    Skv[idx] = f2bf(run);
    run += cv.f;
  }
}

// ---------------- favor_out via MFMA -----------------------------------------
__global__ __launch_bounds__(256) void favor_mfma(
    const uint16_t* __restrict__ qfeat, const uint16_t* __restrict__ kfeat,
    const uint16_t* __restrict__ vbuf, const uint16_t* __restrict__ Skv,
    uint16_t* __restrict__ attn16)
{
  __shared__ uint16_t Vaug[80][136];     // 21760 B
  __shared__ uint16_t A_l[4][32][40];    // 10240 B

  const int c = blockIdx.x, bh = blockIdx.y;
  const int b = bh >> 3, h = bh & 7;
  const int tid = threadIdx.x;
  const int w = tid >> 6, lane = tid & 63;
  const int lr = lane & 15, lg = lane >> 4;
  const size_t srow = (size_t)b * kS + (size_t)c * 128;

#pragma unroll
  for (int i = 0; i < 4; ++i) {
    int idx = tid + 256 * i;
    int u = idx & 127, d = (idx >> 7) * 8;
    uint4 w8 = *(const uint4*)(vbuf + (srow + u) * kD + h * 64 + d);
    Vaug[d + 0][u] = (uint16_t)(w8.x & 0xffff);
    Vaug[d + 1][u] = (uint16_t)(w8.x >> 16);
    Vaug[d + 2][u] = (uint16_t)(w8.y & 0xffff);
    Vaug[d + 3][u] = (uint16_t)(w8.y >> 16);
    Vaug[d + 4][u] = (uint16_t)(w8.z & 0xffff);
    Vaug[d + 5][u] = (uint16_t)(w8.z >> 16);
    Vaug[d + 6][u] = (uint16_t)(w8.w & 0xffff);
    Vaug[d + 7][u] = (uint16_t)(w8.w >> 16);
  }
  if (tid < 128) Vaug[64][tid] = 0x3F80;
  if (tid < 136) {
#pragma unroll
    for (int rr = 65; rr < 80; ++rr) Vaug[rr][tid] = 0;
  }

  bf16x8 qa[2][8];
  const uint16_t* qp = qfeat + ((srow + w * 32 + lr) * kH + h) * kR + 8 * lg;
#pragma unroll
  for (int mf = 0; mf < 2; ++mf)
#pragma unroll
    for (int ks = 0; ks < 8; ++ks)
      qa[mf][ks] = *(const bf16x8*)(qp + (size_t)mf * 16 * (kH * kR) + ks * 32);

  f32x4 o[2][5];
#pragma unroll
  for (int mf = 0; mf < 2; ++mf)
#pragma unroll
    for (int nf = 0; nf < 5; ++nf) o[mf][nf] = (f32x4){0.f, 0.f, 0.f, 0.f};

  const uint16_t* Sg = Skv + ((size_t)bh * kNC + c) * kSST + 8 * lg;
#pragma unroll
  for (int ks = 0; ks < 8; ++ks) {
#pragma unroll
    for (int nf = 0; nf < 5; ++nf) {
      bf16x8 sb = *(const bf16x8*)(Sg + (size_t)(nf * 16 + lr) * 256 + ks * 32);
      o[0][nf] = mfma16(qa[0][ks], sb, o[0][nf]);
      o[1][nf] = mfma16(qa[1][ks], sb, o[1][nf]);
    }
  }

  __syncthreads();

  const uint16_t* kp = kfeat + (srow + lr) * (kH * kR) + h * kR + 8 * lg;
  for (int ut = 0; ut <= w; ++ut) {
    f32x4 aacc[2][2];
#pragma unroll
    for (int mf = 0; mf < 2; ++mf)
#pragma unroll
      for (int nf = 0; nf < 2; ++nf) aacc[mf][nf] = (f32x4){0.f, 0.f, 0.f, 0.f};
#pragma unroll
    for (int ks = 0; ks < 8; ++ks) {
      bf16x8 kb0 = *(const bf16x8*)(kp + (size_t)(ut * 32) * (kH * kR) + ks * 32);
      bf16x8 kb1 = *(const bf16x8*)(kp + (size_t)(ut * 32 + 16) * (kH * kR) + ks * 32);
      aacc[0][0] = mfma16(qa[0][ks], kb0, aacc[0][0]);
      aacc[0][1] = mfma16(qa[0][ks], kb1, aacc[0][1]);
      aacc[1][0] = mfma16(qa[1][ks], kb0, aacc[1][0]);
      aacc[1][1] = mfma16(qa[1][ks], kb1, aacc[1][1]);
    }
#pragma unroll
    for (int mf = 0; mf < 2; ++mf)
#pragma unroll
      for (int nf = 0; nf < 2; ++nf)
#pragma unroll
        for (int reg = 0; reg < 4; ++reg) {
          int trow = mf * 16 + 4 * lg + reg;
          int ucol = nf * 16 + lr;
          float v = aacc[mf][nf][reg];
          if (ut == w && ucol > trow) v = 0.0f;
          A_l[w][trow][ucol] = f2bf(v);
        }
    bf16x8 af0 = *(const bf16x8*)&A_l[w][lr][8 * lg];
    bf16x8 af1 = *(const bf16x8*)&A_l[w][16 + lr][8 * lg];
#pragma unroll
    for (int nf = 0; nf < 5; ++nf) {
      bf16x8 vb = *(const bf16x8*)&Vaug[nf * 16 + lr][ut * 32 + 8 * lg];
      o[0][nf] = mfma16(af0, vb, o[0][nf]);
      o[1][nf] = mfma16(af1, vb, o[1][nf]);
    }
  }

#pragma unroll
  for (int mf = 0; mf < 2; ++mf) {
    float inv[4];
#pragma unroll
    for (int reg = 0; reg < 4; ++reg) {
      float den = __shfl(o[mf][4][reg], lane & 48);
      inv[reg] = 1.0f / (den + kEPS);
    }
    const size_t trow = srow + w * 32 + mf * 16 + 4 * lg;
#pragma unroll
    for (int reg = 0; reg < 4; ++reg) {
      uint16_t* op = attn16 + (trow + reg) * kD + h * 64 + lr;
#pragma unroll
      for (int nf = 0; nf < 4; ++nf)
        op[nf * 16] = f2bf(o[mf][nf][reg] * inv[reg]);
    }
  }
}

// ---------------- launch -----------------------------------------------------
extern "C" void kernel_launch(void* const* d_in, const int* in_sizes, int n_in,
                              void* d_out, int out_size, void* d_ws, size_t ws_size,
                              hipStream_t stream)
{
  (void)in_sizes; (void)n_in; (void)out_size; (void)ws_size;
  const float* x  = (const float*)d_in[0];
  const float* Wq = (const float*)d_in[1];
  const float* Wk = (const float*)d_in[2];
  const float* Wv = (const float*)d_in[3];
  const float* Wo = (const float*)d_in[4];
  const float* bo = (const float*)d_in[5];
  const float* rf = (const float*)d_in[6];
  float* out = (float*)d_out;

  const size_t MiB = 1048576;
  char* ws = (char*)d_ws;
  uint16_t* x16    = (uint16_t*)ws;                    // 16 MiB
  uint16_t* attn16 = (uint16_t*)(ws + 16 * MiB);       // 16 MiB
  uint16_t* v16    = (uint16_t*)(ws + 32 * MiB);       // 16 MiB
  uint16_t* qf     = (uint16_t*)(ws + 48 * MiB);       // 64 MiB
  uint16_t* kf     = (uint16_t*)(ws + 112 * MiB);      // 64 MiB
  uint16_t* Skv    = (uint16_t*)(ws + 176 * MiB);      // 40 MiB
  uint16_t* Wt     = (uint16_t*)(ws + 216 * MiB);      // 2 MiB: Wq^T,Wk^T,Wv^T,Wo^T
  uint16_t* rf16   = (uint16_t*)(ws + 218 * MiB);      // 32 KiB

  cast_inputs<<<dim3(8208, 1, 1), 256, 0, stream>>>(x, rf, x16, rf16);
  transpose_w<<<dim3(8, 8, 4), 256, 0, stream>>>(Wq, Wk, Wv, Wo, Wt);

  // fused q/k projection + features (z=0: q via Wq^T, z=1: k via Wk^T)
  gemm_feat<<<dim3(128, 8, 2), 256, 0, stream>>>(x16, Wt, rf16, qf, kf);

  gemm_bf16<true><<<dim3(128, 8, 1), 256, 0, stream>>>(x16, Wt + 2 * 262144, nullptr, v16);

  chunk_mfma<<<dim3(kNC, kB * kH, 1), 256, 0, stream>>>(kf, v16, Skv);
  prefix_kernel<<<dim3(2560, 1, 1), 256, 0, stream>>>(Skv);
  favor_mfma<<<dim3(kNC, kB * kH, 1), 256, 0, stream>>>(qf, kf, v16, Skv, attn16);

  gemm_bf16<false><<<dim3(128, 8, 1), 256, 0, stream>>>(attn16, Wt + 3 * 262144, bo, out);
}